// Round 18
// baseline (744.037 us; speedup 1.0000x reference)
//
#include <hip/hip_runtime.h>
#include <hip/hip_cooperative_groups.h>

namespace cg = cooperative_groups;

#define N_USERS 100000
#define N_ITEMS 40000
#define NN      140000          // N_NODES
#define N_EDGES 1000000
#define ALPHA   0.2f

typedef short bf16x8 __attribute__((ext_vector_type(8)));
typedef float f32x4  __attribute__((ext_vector_type(4)));

__device__ __forceinline__ unsigned short f2b(float x) {
    unsigned u = __builtin_bit_cast(unsigned, x);
    unsigned r = (u + 0x7FFFu + ((u >> 16) & 1u)) >> 16;
    return (unsigned short)r;
}
__device__ __forceinline__ unsigned cvtpk(float lo, float hi) {   // 2xf32 -> packed bf16 (RNE)
    unsigned r;
    asm("v_cvt_pk_bf16_f32 %0, %1, %2" : "=v"(r) : "v"(lo), "v"(hi));
    return r;
}
__device__ __forceinline__ float blo(unsigned u) { return __builtin_bit_cast(float, u << 16); }
__device__ __forceinline__ float bhi(unsigned u) { return __builtin_bit_cast(float, u & 0xFFFF0000u); }

// async global->LDS, 16B per lane; dest = wave-uniform base + lane*16 (HW rule)
__device__ __forceinline__ void gl_lds16(const void* g, void* l) {
    __builtin_amdgcn_global_load_lds(
        (const __attribute__((address_space(1))) void*)g,
        (__attribute__((address_space(3))) void*)l, 16, 0, 0);
}

// ---------------------------------------------------------------------------
#define PREP_CP   6250
#define PREP_CI   (PREP_CP + 512)
#define PREP_CT   (PREP_CI + 96)
#define PREP_ALL  (PREP_CT + 3907)
#define NU_GEMMFILL (1250 + 3907)
#define NU_PROP     8750

// W[K][64] f32 -> Wt bf16, lane-ordered 1KB chunks
__device__ __forceinline__ int wt_pos(int k, int n) {
    return ((k >> 5) * 4 + (n >> 4)) * 512 + ((((k >> 3) & 3) * 16) + (n & 15)) * 8 + (k & 7);
}

__device__ __forceinline__
void prep_unit(int b, int t, const float* __restrict__ imgp, const float* __restrict__ txtp,
               unsigned short* __restrict__ X,
               const float* __restrict__ Wi, short* __restrict__ WtImg,
               const float* __restrict__ Wx, short* __restrict__ WtTxt,
               const int* __restrict__ ei, int* __restrict__ deg, int* __restrict__ rank)
{
    if (b < PREP_CP) {
        int tid = b * 256 + t;                   // N_USERS*16 8-dim chunks
        if (tid < N_USERS * 16) {
            int i  = tid >> 4;
            int c8 = tid & 15;
            const float* src = (c8 < 8) ? &imgp[(size_t)i * 64 + c8 * 8]
                                        : &txtp[(size_t)i * 64 + (c8 - 8) * 8];
            float4 a = *reinterpret_cast<const float4*>(src);
            float4 c = *reinterpret_cast<const float4*>(src + 4);
            int4 o = make_int4((int)cvtpk(a.x, a.y), (int)cvtpk(a.z, a.w),
                               (int)cvtpk(c.x, c.y), (int)cvtpk(c.z, c.w));
            *reinterpret_cast<int4*>(&X[(size_t)i * 128 + c8 * 8]) = o;
        }
    } else if (b < PREP_CI) {
        int tid = (b - PREP_CP) * 256 + t;       // 2048*64
        int k = tid >> 6, n = tid & 63;
        WtImg[wt_pos(k, n)] = (short)f2b(Wi[tid]);
    } else if (b < PREP_CT) {
        int tid = (b - PREP_CI) * 256 + t;       // 384*64
        if (tid < 384 * 64) {
            int k = tid >> 6, n = tid & 63;
            WtTxt[wt_pos(k, n)] = (short)f2b(Wx[tid]);
        }
    } else {
        int e = (b - PREP_CT) * 256 + t;
        if (e < N_EDGES) {
            int d = ei[N_EDGES + e];
            int r = atomicAdd(&deg[d], 1);       // histogram AND this edge's rank
            rank[e] = r;
        }
    }
}

__device__ __forceinline__
void scan1_unit(int b, int t, int* ts, const int* __restrict__ deg,
                int* __restrict__ row_ptr, int* __restrict__ blockSums)
{
    int base = b * 1024 + t * 4;
    int v[4]; int s = 0;
    #pragma unroll
    for (int j = 0; j < 4; j++) {
        v[j] = (base + j < NN) ? deg[base + j] : 0;
        s += v[j];
    }
    ts[t] = s;
    __syncthreads();
    for (int off = 1; off < 256; off <<= 1) {
        int x = (t >= off) ? ts[t - off] : 0;
        __syncthreads();
        ts[t] += x;
        __syncthreads();
    }
    int excl = ts[t] - s;
    int run = excl;
    #pragma unroll
    for (int j = 0; j < 4; j++) {
        if (base + j < NN) row_ptr[base + j] = run;
        run += v[j];
    }
    if (t == 255) blockSums[b] = ts[255];
    __syncthreads();                     // ts reused by next unit
}

__device__ __forceinline__
void scan23_unit(int b, int t, int* ts, const int* __restrict__ blockSums,
                 int* __restrict__ row_ptr)
{
    ts[t] = (t < b) ? blockSums[t] : 0;  // b <= 136 < 256
    __syncthreads();
    for (int off = 128; off > 0; off >>= 1) {
        if (t < off) ts[t] += ts[t + off];
        __syncthreads();
    }
    int off0 = ts[0];
    int base = b * 1024 + t * 4;
    #pragma unroll
    for (int j = 0; j < 4; j++) {
        int idx = base + j;
        if (idx < NN) row_ptr[idx] += off0;
    }
    if (b == 0 && t == 0) row_ptr[NN] = N_EDGES;
    __syncthreads();                     // ts reused by next unit
}

// ---------------------------------------------------------------------------
// MFMA GEMM unit, all-LDS compute, counted-vmcnt pipeline (R15-proven).
template<int K, int COLOFF>
__device__ __forceinline__
void gemm_body(int bx, const float* __restrict__ A, const short* __restrict__ Wt,
               const float* __restrict__ bias, unsigned short* __restrict__ X,
               float* ldsA, short* ldsB)
{
    constexpr int NT = K / 64;        // tiles: img 32, txt 6
    const int t    = threadIdx.x;     // 0..255
    const int wid  = t >> 6;
    const int lane = t & 63;
    const int lo   = lane & 15;
    const int g    = lane >> 4;
    const int r0   = bx * 64;

    f32x4 acc[4];
    #pragma unroll
    for (int ct = 0; ct < 4; ++ct) acc[ct] = (f32x4){0.f, 0.f, 0.f, 0.f};

    auto stage = [&](int buf, int kt) {
        int k0 = kt * 64;
        #pragma unroll
        for (int i = 0; i < 4; ++i) {
            int c     = i * 4 + wid;               // A chunk (4 rows x 16 units)
            int row_t = c * 4 + g;
            int u_log = lo ^ (row_t & 15);
            const float* gp = A + (size_t)(r0 + row_t) * K + k0 + u_log * 4;
            gl_lds16(gp, ldsA + buf * 4096 + c * 256);
        }
        #pragma unroll
        for (int i2 = 0; i2 < 2; ++i2) {
            int c2 = i2 * 4 + wid;                 // B chunk (lane-ordered 1KB)
            const short* gp = Wt + ((size_t)kt * 8 + c2) * 512 + lane * 8;
            gl_lds16(gp, ldsB + buf * 4096 + c2 * 512);
        }
    };

    auto compute = [&](int buf) {
        int row_t = wid * 16 + lo;
        const float* baseA = ldsA + buf * 4096 + row_t * 64;
        const short* baseB = ldsB + buf * 4096;
        #pragma unroll
        for (int m = 0; m < 2; ++m) {
            int u0 = (m * 8 + 2 * g) ^ lo;         // swizzled A read
            int u1 = (m * 8 + 2 * g + 1) ^ lo;
            float4 xa = *reinterpret_cast<const float4*>(baseA + u0 * 4);
            float4 ya = *reinterpret_cast<const float4*>(baseA + u1 * 4);
            int4 ai = make_int4((int)cvtpk(xa.x, xa.y), (int)cvtpk(xa.z, xa.w),
                                (int)cvtpk(ya.x, ya.y), (int)cvtpk(ya.z, ya.w));
            bf16x8 a = __builtin_bit_cast(bf16x8, ai);
            #pragma unroll
            for (int ct = 0; ct < 4; ++ct) {
                int4 w = *reinterpret_cast<const int4*>(baseB + (m * 4 + ct) * 512 + lane * 8);
                bf16x8 bb = __builtin_bit_cast(bf16x8, w);
                acc[ct] = __builtin_amdgcn_mfma_f32_16x16x32_bf16(a, bb, acc[ct], 0, 0, 0);
            }
        }
    };

    stage(0, 0);                                    // 6 loads in flight
    for (int kt = 0; kt < NT; ++kt) {
        if (kt + 1 < NT) {
            stage((kt + 1) & 1, kt + 1);            // +6 loads
            asm volatile("s_waitcnt vmcnt(6)" ::: "memory");   // tile kt landed
        } else {
            asm volatile("s_waitcnt vmcnt(0)" ::: "memory");
        }
        __builtin_amdgcn_s_barrier();
        __builtin_amdgcn_sched_barrier(0);
        compute(kt & 1);
        __builtin_amdgcn_s_barrier();
    }

    float bia[4];
    #pragma unroll
    for (int ct = 0; ct < 4; ++ct) bia[ct] = bias[ct * 16 + lo];

    int r0w = r0 + wid * 16;
    #pragma unroll
    for (int r = 0; r < 4; ++r) {
        float v[4];
        float ss = 0.f;
        #pragma unroll
        for (int ct = 0; ct < 4; ++ct) { v[ct] = acc[ct][r] + bia[ct]; ss += v[ct] * v[ct]; }
        ss += __shfl_xor(ss, 1);
        ss += __shfl_xor(ss, 2);
        ss += __shfl_xor(ss, 4);
        ss += __shfl_xor(ss, 8);
        float sc = 1.0f / fmaxf(sqrtf(ss), 1e-12f);
        int grow = r0w + g * 4 + r;
        unsigned short* dst = &X[(size_t)(N_USERS + grow) * 128 + COLOFF + lo];
        #pragma unroll
        for (int ct = 0; ct < 4; ++ct) dst[ct * 16] = f2b(v[ct] * sc);
    }
}

// ---------------------------------------------------------------------------
// Propagation unit: one 16-lane group per node (16 nodes/unit/block).
template<bool FINAL>
__device__ __forceinline__
void prop_unit(int u, int t, const unsigned short* __restrict__ Xin,
               const int* __restrict__ row_ptr, const int2* __restrict__ epk,
               void* __restrict__ outv)
{
    int lane = t & 63;
    int gl   = lane & 15;
    int gb   = lane & 48;
    int node = u * 16 + (t >> 4);              // NU_PROP*16 = NN exactly
    int e0 = row_ptr[node];
    int e1 = row_ptr[node + 1];
    float a0 = 0.f, a1 = 0.f, a2 = 0.f, a3 = 0.f;
    float a4 = 0.f, a5 = 0.f, a6 = 0.f, a7 = 0.f;

    for (int base = e0; base < e1; base += 16) {
        int cnt = e1 - base; if (cnt > 16) cnt = 16;
        int sv = 0, wvb = 0;
        if (base + gl < e1) {
            int2 ev = epk[base + gl];
            sv = ev.x; wvb = ev.y;
        }
        float wv = __builtin_bit_cast(float, wvb);
        int i = 0;
        for (; i + 1 < cnt; i += 2) {
            int   s0 = __shfl(sv, gb + i);
            int   s1 = __shfl(sv, gb + i + 1);
            float w0 = __shfl(wv, gb + i);
            float w1 = __shfl(wv, gb + i + 1);
            uint4 u0 = *reinterpret_cast<const uint4*>(&Xin[(size_t)s0 * 128 + gl * 8]);
            uint4 u1 = *reinterpret_cast<const uint4*>(&Xin[(size_t)s1 * 128 + gl * 8]);
            a0 = fmaf(w0, blo(u0.x), a0); a1 = fmaf(w0, bhi(u0.x), a1);
            a2 = fmaf(w0, blo(u0.y), a2); a3 = fmaf(w0, bhi(u0.y), a3);
            a4 = fmaf(w0, blo(u0.z), a4); a5 = fmaf(w0, bhi(u0.z), a5);
            a6 = fmaf(w0, blo(u0.w), a6); a7 = fmaf(w0, bhi(u0.w), a7);
            a0 = fmaf(w1, blo(u1.x), a0); a1 = fmaf(w1, bhi(u1.x), a1);
            a2 = fmaf(w1, blo(u1.y), a2); a3 = fmaf(w1, bhi(u1.y), a3);
            a4 = fmaf(w1, blo(u1.z), a4); a5 = fmaf(w1, bhi(u1.z), a5);
            a6 = fmaf(w1, blo(u1.w), a6); a7 = fmaf(w1, bhi(u1.w), a7);
        }
        if (i < cnt) {
            int   s0 = __shfl(sv, gb + i);
            float w0 = __shfl(wv, gb + i);
            uint4 u0 = *reinterpret_cast<const uint4*>(&Xin[(size_t)s0 * 128 + gl * 8]);
            a0 = fmaf(w0, blo(u0.x), a0); a1 = fmaf(w0, bhi(u0.x), a1);
            a2 = fmaf(w0, blo(u0.y), a2); a3 = fmaf(w0, bhi(u0.y), a3);
            a4 = fmaf(w0, blo(u0.z), a4); a5 = fmaf(w0, bhi(u0.z), a5);
            a6 = fmaf(w0, blo(u0.w), a6); a7 = fmaf(w0, bhi(u0.w), a7);
        }
    }

    uint4 us = *reinterpret_cast<const uint4*>(&Xin[(size_t)node * 128 + gl * 8]);
    a0 += ALPHA * blo(us.x); a1 += ALPHA * bhi(us.x);
    a2 += ALPHA * blo(us.y); a3 += ALPHA * bhi(us.y);
    a4 += ALPHA * blo(us.z); a5 += ALPHA * bhi(us.z);
    a6 += ALPHA * blo(us.w); a7 += ALPHA * bhi(us.w);

    if (!FINAL) {
        unsigned short* out = (unsigned short*)outv;
        uint4 p;
        p.x = cvtpk(a0, a1); p.y = cvtpk(a2, a3);
        p.z = cvtpk(a4, a5); p.w = cvtpk(a6, a7);
        *reinterpret_cast<uint4*>(&out[(size_t)node * 128 + gl * 8]) = p;
    } else {
        float* out = (float*)outv;
        int d = gl * 8;
        float* dst = (d < 64) ? &out[(size_t)node * 64 + d]
                              : &out[(size_t)NN * 64 + (size_t)node * 64 + (d - 64)];
        *reinterpret_cast<float4*>(dst)     = make_float4(a0, a1, a2, a3);
        *reinterpret_cast<float4*>(dst + 4) = make_float4(a4, a5, a6, a7);
    }
}

// ---------------------------------------------------------------------------
// The whole pipeline as ONE cooperative kernel; phases split by grid.sync().
__global__ __launch_bounds__(256, 3)
void mega(const int* __restrict__ ei, const float* __restrict__ ew,
          const float* __restrict__ Ai, const float* __restrict__ Ax,
          const float* __restrict__ Wi, const float* __restrict__ bi,
          const float* __restrict__ Wx, const float* __restrict__ bx,
          const float* __restrict__ imgp, const float* __restrict__ txtp,
          float* __restrict__ out,
          unsigned short* __restrict__ Xa, unsigned short* __restrict__ Xb,
          int* __restrict__ deg, int* __restrict__ row_ptr,
          int* __restrict__ rank, int2* __restrict__ epk,
          int* __restrict__ bsums,
          short* __restrict__ WtImg, short* __restrict__ WtTxt)
{
    __shared__ union {
        struct { float A[8192]; __align__(16) short B[8192]; } g;  // 48KB GEMM
        int ts[256];                                               // scans
    } sh;

    cg::grid_group grid = cg::this_grid();
    const int bid = blockIdx.x, t = threadIdx.x, nb = gridDim.x;

    // phase 0: zero deg
    for (int i = bid * 256 + t; i < NN; i += nb * 256) deg[i] = 0;
    __threadfence();
    grid.sync();

    // phase 1: prep (copy_pref | conv_w | hist+rank)
    for (int u = bid; u < PREP_ALL; u += nb)
        prep_unit(u, t, imgp, txtp, Xa, Wi, WtImg, Wx, WtTxt, ei, deg, rank);
    __threadfence();
    grid.sync();

    // phase 2: scan1
    for (int u = bid; u < 137; u += nb)
        scan1_unit(u, t, sh.ts, deg, row_ptr, bsums);
    __threadfence();
    grid.sync();

    // phase 3: scan23
    for (int u = bid; u < 137; u += nb)
        scan23_unit(u, t, sh.ts, bsums, row_ptr);
    __threadfence();
    grid.sync();

    // phase 4: gemm (units 0..1249) + fill (units 1250..)
    for (int u = bid; u < NU_GEMMFILL; u += nb) {
        if (u < 625)       gemm_body<2048, 0 >(u, Ai, WtImg, bi, Xa, sh.g.A, sh.g.B);
        else if (u < 1250) gemm_body< 384, 64>(u - 625, Ax, WtTxt, bx, Xa, sh.g.A, sh.g.B);
        else {
            int e = (u - 1250) * 256 + t;
            if (e < N_EDGES) {
                int s = ei[e];
                int d = ei[N_EDGES + e];
                epk[row_ptr[d] + rank[e]] = make_int2(s, __builtin_bit_cast(int, ew[e]));
            }
        }
    }
    __threadfence();
    grid.sync();

    // phase 5: propagate layer 1 (bf16 out)
    for (int u = bid; u < NU_PROP; u += nb)
        prop_unit<false>(u, t, Xa, row_ptr, epk, Xb);
    __threadfence();
    grid.sync();

    // phase 6: propagate layer 2 (f32 split out)
    for (int u = bid; u < NU_PROP; u += nb)
        prop_unit<true>(u, t, Xb, row_ptr, epk, out);
}

// ---------------------------------------------------------------------------
extern "C" void kernel_launch(void* const* d_in, const int* in_sizes, int n_in,
                              void* d_out, int out_size, void* d_ws, size_t ws_size,
                              hipStream_t stream)
{
    const int*   ei       = (const int*)d_in[0];
    const float* ew       = (const float*)d_in[1];
    const float* img_feat = (const float*)d_in[2];
    const float* txt_feat = (const float*)d_in[3];
    const float* img_w    = (const float*)d_in[4];
    const float* img_b    = (const float*)d_in[5];
    const float* txt_w    = (const float*)d_in[6];
    const float* txt_b    = (const float*)d_in[7];
    const float* img_pref = (const float*)d_in[8];
    const float* txt_pref = (const float*)d_in[9];
    float* out = (float*)d_out;

    const size_t XBYTES = (size_t)NN * 128 * 2;      // bf16
    char* ws = (char*)d_ws;
    size_t off = 0;
    auto alloc = [&](size_t bytes) -> void* {
        void* p = ws + off;
        off = (off + bytes + 255) & ~(size_t)255;
        return p;
    };
    unsigned short* Xa = (unsigned short*)alloc(XBYTES);
    unsigned short* Xb = (unsigned short*)alloc(XBYTES);
    int*   deg     = (int*)alloc((size_t)NN * 4);
    int*   row_ptr = (int*)alloc((size_t)(NN + 1) * 4);
    int*   rank    = (int*)alloc((size_t)N_EDGES * 4);
    int2*  epk     = (int2*)alloc((size_t)N_EDGES * 8);
    int*   bsums   = (int*)alloc(256 * 4);
    short* WtImg   = (short*)alloc((size_t)2048 * 64 * 2);
    short* WtTxt   = (short*)alloc((size_t)384 * 64 * 2);

    int maxb = 0;
    hipOccupancyMaxActiveBlocksPerMultiprocessor(&maxb, mega, 256, 0);
    if (maxb < 1) maxb = 1;
    int nb = maxb * 256;               // 256 CUs on MI355X
    if (nb > 2048) nb = 2048;

    void* args[] = {
        (void*)&ei, (void*)&ew, (void*)&img_feat, (void*)&txt_feat,
        (void*)&img_w, (void*)&img_b, (void*)&txt_w, (void*)&txt_b,
        (void*)&img_pref, (void*)&txt_pref, (void*)&out,
        (void*)&Xa, (void*)&Xb, (void*)&deg, (void*)&row_ptr,
        (void*)&rank, (void*)&epk, (void*)&bsums, (void*)&WtImg, (void*)&WtTxt
    };
    hipLaunchCooperativeKernel((const void*)mega, dim3(nb), dim3(256),
                               args, 0, stream);
}

// Round 19
// 293.368 us; speedup vs baseline: 2.5362x; 2.5362x over previous
//
#include <hip/hip_runtime.h>

#define N_USERS 100000
#define N_ITEMS 40000
#define NN      140000          // N_NODES
#define N_EDGES 1000000
#define ALPHA   0.2f

typedef short bf16x8 __attribute__((ext_vector_type(8)));
typedef float f32x4  __attribute__((ext_vector_type(4)));

__device__ __forceinline__ unsigned short f2b(float x) {
    unsigned u = __builtin_bit_cast(unsigned, x);
    unsigned r = (u + 0x7FFFu + ((u >> 16) & 1u)) >> 16;
    return (unsigned short)r;
}
__device__ __forceinline__ unsigned cvtpk(float lo, float hi) {   // 2xf32 -> packed bf16 (RNE)
    unsigned r;
    asm("v_cvt_pk_bf16_f32 %0, %1, %2" : "=v"(r) : "v"(lo), "v"(hi));
    return r;
}
__device__ __forceinline__ float blo(unsigned u) { return __builtin_bit_cast(float, u << 16); }
__device__ __forceinline__ float bhi(unsigned u) { return __builtin_bit_cast(float, u & 0xFFFF0000u); }

// async global->LDS, 16B per lane; dest = wave-uniform base + lane*16 (HW rule)
__device__ __forceinline__ void gl_lds16(const void* g, void* l) {
    __builtin_amdgcn_global_load_lds(
        (const __attribute__((address_space(1))) void*)g,
        (__attribute__((address_space(3))) void*)l, 16, 0, 0);
}

// ---------------------------------------------------------------------------
// prep: block-range fused  [copy_pref | conv_w(img) | conv_w(txt) | hist+rank]
#define PREP_CP   6250
#define PREP_CI   (PREP_CP + 512)
#define PREP_CT   (PREP_CI + 96)
#define PREP_ALL  (PREP_CT + 3907)

// W[K][64] f32 -> Wt bf16, lane-ordered 1KB chunks:
// chunk = (k>>5)*4 + (n>>4); lane = ((k>>3)&3)*16 + (n&15); j = k&7
__device__ __forceinline__ int wt_pos(int k, int n) {
    return ((k >> 5) * 4 + (n >> 4)) * 512 + ((((k >> 3) & 3) * 16) + (n & 15)) * 8 + (k & 7);
}

__global__ __launch_bounds__(256)
void prep(const float* __restrict__ imgp, const float* __restrict__ txtp,
          unsigned short* __restrict__ X,
          const float* __restrict__ Wi, short* __restrict__ WtImg,
          const float* __restrict__ Wx, short* __restrict__ WtTxt,
          const int* __restrict__ ei, int* __restrict__ deg,
          int* __restrict__ rank)
{
    int b = blockIdx.x, t = threadIdx.x;
    if (b < PREP_CP) {
        int tid = b * 256 + t;                   // N_USERS*16 8-dim chunks
        if (tid >= N_USERS * 16) return;
        int i  = tid >> 4;
        int c8 = tid & 15;
        const float* src = (c8 < 8) ? &imgp[(size_t)i * 64 + c8 * 8]
                                    : &txtp[(size_t)i * 64 + (c8 - 8) * 8];
        float4 a = *reinterpret_cast<const float4*>(src);
        float4 c = *reinterpret_cast<const float4*>(src + 4);
        int4 o = make_int4((int)cvtpk(a.x, a.y), (int)cvtpk(a.z, a.w),
                           (int)cvtpk(c.x, c.y), (int)cvtpk(c.z, c.w));
        *reinterpret_cast<int4*>(&X[(size_t)i * 128 + c8 * 8]) = o;
    } else if (b < PREP_CI) {
        int tid = (b - PREP_CP) * 256 + t;       // 2048*64
        int k = tid >> 6, n = tid & 63;
        WtImg[wt_pos(k, n)] = (short)f2b(Wi[tid]);
    } else if (b < PREP_CT) {
        int tid = (b - PREP_CI) * 256 + t;       // 384*64
        if (tid >= 384 * 64) return;
        int k = tid >> 6, n = tid & 63;
        WtTxt[wt_pos(k, n)] = (short)f2b(Wx[tid]);
    } else {
        int e = (b - PREP_CT) * 256 + t;
        if (e < N_EDGES) {
            int d = ei[N_EDGES + e];
            int r = atomicAdd(&deg[d], 1);       // histogram AND this edge's rank
            rank[e] = r;                         // fire-and-forget store
        }
    }
}

// ---------------------------------------------------------------------------
// MFMA GEMM, all-LDS compute, counted-vmcnt pipeline. BK=128: A tile
// 64r x 128k f32 (32KB, 512B/row granule), B tile 16KB; double-buffered 96KB.
// 4 waves/block, wave = 16r x 64c; 12 stage-insts/wave/tile -> vmcnt(12).
template<int K, int COLOFF>
__device__ __forceinline__
void gemm_body(int bx, const float* __restrict__ A, const short* __restrict__ Wt,
               const float* __restrict__ bias, unsigned short* __restrict__ X,
               float* ldsA, short* ldsB)
{
    constexpr int NT = K / 128;       // tiles: img 16, txt 3
    const int t    = threadIdx.x;     // 0..255
    const int wid  = t >> 6;
    const int lane = t & 63;
    const int lo   = lane & 15;
    const int g    = lane >> 4;
    const int r0   = bx * 64;

    f32x4 acc[4];
    #pragma unroll
    for (int ct = 0; ct < 4; ++ct) acc[ct] = (f32x4){0.f, 0.f, 0.f, 0.f};

    // A: 32 chunks of 1KB (2 rows x 512B each); chunk c -> rows c*2+(lane>>5),
    // unit-in-row = lane&31, global unit = phys ^ (row&15)  [XOR swizzle]
    // B: 16 lane-ordered 1KB chunks per tile (Wt chunks kt*16 .. +15)
    auto stage = [&](int buf, int kt) {
        int k0 = kt * 128;
        #pragma unroll
        for (int i = 0; i < 8; ++i) {
            int c     = i * 4 + wid;
            int row_t = c * 2 + (lane >> 5);
            int u_log = (lane & 31) ^ (row_t & 15);
            const float* gp = A + (size_t)(r0 + row_t) * K + k0 + u_log * 4;
            gl_lds16(gp, ldsA + buf * 8192 + c * 256);
        }
        #pragma unroll
        for (int i2 = 0; i2 < 4; ++i2) {
            int c2 = i2 * 4 + wid;
            const short* gp = Wt + ((size_t)kt * 16 + c2) * 512 + lane * 8;
            gl_lds16(gp, ldsB + buf * 8192 + c2 * 512);
        }
    };

    // compute one tile: 4 MFMA k-steps (K=32 each), all operands from LDS
    auto compute = [&](int buf) {
        int row_t = wid * 16 + lo;
        const float* baseA = ldsA + buf * 8192 + row_t * 128;
        const short* baseB = ldsB + buf * 8192;
        #pragma unroll
        for (int m = 0; m < 4; ++m) {
            int u0 = (m * 8 + 2 * g) ^ lo;         // swizzled A read (32 units/row)
            int u1 = (m * 8 + 2 * g + 1) ^ lo;
            float4 xa = *reinterpret_cast<const float4*>(baseA + u0 * 4);
            float4 ya = *reinterpret_cast<const float4*>(baseA + u1 * 4);
            int4 ai = make_int4((int)cvtpk(xa.x, xa.y), (int)cvtpk(xa.z, xa.w),
                                (int)cvtpk(ya.x, ya.y), (int)cvtpk(ya.z, ya.w));
            bf16x8 a = __builtin_bit_cast(bf16x8, ai);
            #pragma unroll
            for (int ct = 0; ct < 4; ++ct) {
                int4 w = *reinterpret_cast<const int4*>(baseB + (m * 4 + ct) * 512 + lane * 8);
                bf16x8 bb = __builtin_bit_cast(bf16x8, w);
                acc[ct] = __builtin_amdgcn_mfma_f32_16x16x32_bf16(a, bb, acc[ct], 0, 0, 0);
            }
        }
    };

    stage(0, 0);                                    // 12 loads in flight
    for (int kt = 0; kt < NT; ++kt) {
        if (kt + 1 < NT) {
            stage((kt + 1) & 1, kt + 1);            // +12 loads (24 outstanding)
            asm volatile("s_waitcnt vmcnt(12)" ::: "memory");  // tile kt landed
        } else {
            asm volatile("s_waitcnt vmcnt(0)" ::: "memory");
        }
        __builtin_amdgcn_s_barrier();               // all waves' kt data in LDS
        __builtin_amdgcn_sched_barrier(0);
        compute(kt & 1);
        __builtin_amdgcn_s_barrier();               // reads done before buf reuse
    }

    float bia[4];
    #pragma unroll
    for (int ct = 0; ct < 4; ++ct) bia[ct] = bias[ct * 16 + lo];

    int r0w = r0 + wid * 16;
    #pragma unroll
    for (int r = 0; r < 4; ++r) {
        float v[4];
        float ss = 0.f;
        #pragma unroll
        for (int ct = 0; ct < 4; ++ct) { v[ct] = acc[ct][r] + bia[ct]; ss += v[ct] * v[ct]; }
        ss += __shfl_xor(ss, 1);
        ss += __shfl_xor(ss, 2);
        ss += __shfl_xor(ss, 4);
        ss += __shfl_xor(ss, 8);
        float sc = 1.0f / fmaxf(sqrtf(ss), 1e-12f);
        int grow = r0w + g * 4 + r;
        unsigned short* dst = &X[(size_t)(N_USERS + grow) * 128 + COLOFF + lo];
        #pragma unroll
        for (int ct = 0; ct < 4; ++ct) dst[ct * 16] = f2b(v[ct] * sc);
    }
}

// Fused: blocks 0..624 img GEMM, 625..1249 txt GEMM, 1250.. fill (atomic-free)
__global__ __launch_bounds__(256)
void gemm_fill(const float* __restrict__ Ai, const short* __restrict__ WtImg,
               const float* __restrict__ bi,
               const float* __restrict__ Ax, const short* __restrict__ WtTxt,
               const float* __restrict__ bx, unsigned short* __restrict__ X,
               const int* __restrict__ ei, const float* __restrict__ ew,
               const int* __restrict__ row_ptr, const int* __restrict__ rank,
               int2* __restrict__ epk)
{
    __shared__ float ldsA[16384];                  // 2 x 32KB
    __shared__ __align__(16) short ldsB[16384];    // 2 x 16KB
    int b = blockIdx.x;
    if (b < 625)       gemm_body<2048, 0 >(b, Ai, WtImg, bi, X, ldsA, ldsB);
    else if (b < 1250) gemm_body< 384, 64>(b - 625, Ax, WtTxt, bx, X, ldsA, ldsB);
    else {
        int e = (b - 1250) * 256 + threadIdx.x;
        if (e >= N_EDGES) return;
        int s = ei[e];
        int d = ei[N_EDGES + e];
        int p = row_ptr[d] + rank[e];              // no atomic, no round-trip
        epk[p] = make_int2(s, __builtin_bit_cast(int, ew[e]));
    }
}

// ---------------------------------------------------------------------------
// CSR scans
__global__ void scan1(const int* __restrict__ deg, int* __restrict__ row_ptr,
                      int* __restrict__ blockSums)
{
    __shared__ int ts[256];
    int t = threadIdx.x, b = blockIdx.x;
    int base = b * 1024 + t * 4;
    int v[4]; int s = 0;
    #pragma unroll
    for (int j = 0; j < 4; j++) {
        v[j] = (base + j < NN) ? deg[base + j] : 0;
        s += v[j];
    }
    ts[t] = s;
    __syncthreads();
    for (int off = 1; off < 256; off <<= 1) {
        int x = (t >= off) ? ts[t - off] : 0;
        __syncthreads();
        ts[t] += x;
        __syncthreads();
    }
    int excl = ts[t] - s;
    int run = excl;
    #pragma unroll
    for (int j = 0; j < 4; j++) {
        if (base + j < NN) row_ptr[base + j] = run;
        run += v[j];
    }
    if (t == 255) blockSums[b] = ts[255];
}

// merged scan2+scan3: each block re-reduces blockSums[0..b-1] (137 entries)
__global__ void scan23(const int* __restrict__ blockSums, int* __restrict__ row_ptr)
{
    __shared__ int ts[256];
    int t = threadIdx.x, b = blockIdx.x;
    ts[t] = (t < b) ? blockSums[t] : 0;     // b <= 136 < 256
    __syncthreads();
    for (int off = 128; off > 0; off >>= 1) {
        if (t < off) ts[t] += ts[t + off];
        __syncthreads();
    }
    int off0 = ts[0];
    int base = b * 1024 + t * 4;
    #pragma unroll
    for (int j = 0; j < 4; j++) {
        int idx = base + j;
        if (idx < NN) row_ptr[idx] += off0;
    }
    if (b == 0 && t == 0) row_ptr[NN] = N_EDGES;
}

// ---------------------------------------------------------------------------
// Propagation: one 16-LANE GROUP per node (4 nodes/wave, 16 nodes/block).
// Lane owns 8 of 128 dims (one uint4 = 16B gather per edge).
// FINAL=true writes f32 split [2][NN][64] output.
template<bool FINAL>
__global__ __launch_bounds__(256)
void propagate(const unsigned short* __restrict__ Xin, const int* __restrict__ row_ptr,
               const int2* __restrict__ epk, void* __restrict__ outv)
{
    int lane = threadIdx.x & 63;
    int gl   = lane & 15;                      // lane within group
    int gb   = lane & 48;                      // group base lane (abs in wave)
    int node = blockIdx.x * 16 + (threadIdx.x >> 4);   // 8750*16 = NN exactly
    int e0 = row_ptr[node];
    int e1 = row_ptr[node + 1];
    float a0 = 0.f, a1 = 0.f, a2 = 0.f, a3 = 0.f;
    float a4 = 0.f, a5 = 0.f, a6 = 0.f, a7 = 0.f;

    for (int base = e0; base < e1; base += 16) {
        int cnt = e1 - base; if (cnt > 16) cnt = 16;
        int sv = 0, wvb = 0;
        if (base + gl < e1) {
            int2 ev = epk[base + gl];
            sv = ev.x; wvb = ev.y;
        }
        float wv = __builtin_bit_cast(float, wvb);
        int i = 0;
        for (; i + 1 < cnt; i += 2) {
            int   s0 = __shfl(sv, gb + i);
            int   s1 = __shfl(sv, gb + i + 1);
            float w0 = __shfl(wv, gb + i);
            float w1 = __shfl(wv, gb + i + 1);
            uint4 u0 = *reinterpret_cast<const uint4*>(&Xin[(size_t)s0 * 128 + gl * 8]);
            uint4 u1 = *reinterpret_cast<const uint4*>(&Xin[(size_t)s1 * 128 + gl * 8]);
            a0 = fmaf(w0, blo(u0.x), a0); a1 = fmaf(w0, bhi(u0.x), a1);
            a2 = fmaf(w0, blo(u0.y), a2); a3 = fmaf(w0, bhi(u0.y), a3);
            a4 = fmaf(w0, blo(u0.z), a4); a5 = fmaf(w0, bhi(u0.z), a5);
            a6 = fmaf(w0, blo(u0.w), a6); a7 = fmaf(w0, bhi(u0.w), a7);
            a0 = fmaf(w1, blo(u1.x), a0); a1 = fmaf(w1, bhi(u1.x), a1);
            a2 = fmaf(w1, blo(u1.y), a2); a3 = fmaf(w1, bhi(u1.y), a3);
            a4 = fmaf(w1, blo(u1.z), a4); a5 = fmaf(w1, bhi(u1.z), a5);
            a6 = fmaf(w1, blo(u1.w), a6); a7 = fmaf(w1, bhi(u1.w), a7);
        }
        if (i < cnt) {
            int   s0 = __shfl(sv, gb + i);
            float w0 = __shfl(wv, gb + i);
            uint4 u0 = *reinterpret_cast<const uint4*>(&Xin[(size_t)s0 * 128 + gl * 8]);
            a0 = fmaf(w0, blo(u0.x), a0); a1 = fmaf(w0, bhi(u0.x), a1);
            a2 = fmaf(w0, blo(u0.y), a2); a3 = fmaf(w0, bhi(u0.y), a3);
            a4 = fmaf(w0, blo(u0.z), a4); a5 = fmaf(w0, bhi(u0.z), a5);
            a6 = fmaf(w0, blo(u0.w), a6); a7 = fmaf(w0, bhi(u0.w), a7);
        }
    }

    uint4 us = *reinterpret_cast<const uint4*>(&Xin[(size_t)node * 128 + gl * 8]);
    a0 += ALPHA * blo(us.x); a1 += ALPHA * bhi(us.x);
    a2 += ALPHA * blo(us.y); a3 += ALPHA * bhi(us.y);
    a4 += ALPHA * blo(us.z); a5 += ALPHA * bhi(us.z);
    a6 += ALPHA * blo(us.w); a7 += ALPHA * bhi(us.w);

    if (!FINAL) {
        unsigned short* out = (unsigned short*)outv;
        uint4 p;
        p.x = cvtpk(a0, a1); p.y = cvtpk(a2, a3);
        p.z = cvtpk(a4, a5); p.w = cvtpk(a6, a7);
        *reinterpret_cast<uint4*>(&out[(size_t)node * 128 + gl * 8]) = p;
    } else {
        float* out = (float*)outv;
        int d = gl * 8;
        float* dst = (d < 64) ? &out[(size_t)node * 64 + d]
                              : &out[(size_t)NN * 64 + (size_t)node * 64 + (d - 64)];
        *reinterpret_cast<float4*>(dst)     = make_float4(a0, a1, a2, a3);
        *reinterpret_cast<float4*>(dst + 4) = make_float4(a4, a5, a6, a7);
    }
}

// ---------------------------------------------------------------------------
extern "C" void kernel_launch(void* const* d_in, const int* in_sizes, int n_in,
                              void* d_out, int out_size, void* d_ws, size_t ws_size,
                              hipStream_t stream)
{
    const int*   ei       = (const int*)d_in[0];
    const float* ew       = (const float*)d_in[1];
    const float* img_feat = (const float*)d_in[2];
    const float* txt_feat = (const float*)d_in[3];
    const float* img_w    = (const float*)d_in[4];
    const float* img_b    = (const float*)d_in[5];
    const float* txt_w    = (const float*)d_in[6];
    const float* txt_b    = (const float*)d_in[7];
    const float* img_pref = (const float*)d_in[8];
    const float* txt_pref = (const float*)d_in[9];
    float* out = (float*)d_out;

    const size_t XBYTES = (size_t)NN * 128 * 2;      // bf16
    char* ws = (char*)d_ws;
    size_t off = 0;
    auto alloc = [&](size_t bytes) -> void* {
        void* p = ws + off;
        off = (off + bytes + 255) & ~(size_t)255;
        return p;
    };
    unsigned short* Xa = (unsigned short*)alloc(XBYTES);
    unsigned short* Xb = (unsigned short*)alloc(XBYTES);
    int*   deg     = (int*)alloc((size_t)NN * 4);
    int*   row_ptr = (int*)alloc((size_t)(NN + 1) * 4);
    int*   rank    = (int*)alloc((size_t)N_EDGES * 4);
    int2*  epk     = (int2*)alloc((size_t)N_EDGES * 8);
    int*   bsums   = (int*)alloc(256 * 4);
    short* WtImg   = (short*)alloc((size_t)2048 * 64 * 2);
    short* WtTxt   = (short*)alloc((size_t)384 * 64 * 2);

    hipMemsetAsync(deg, 0, (size_t)NN * 4, stream);

    prep<<<PREP_ALL, 256, 0, stream>>>(img_pref, txt_pref, Xa,
                                       img_w, WtImg, txt_w, WtTxt, ei, deg, rank);

    scan1<<<137, 256, 0, stream>>>(deg, row_ptr, bsums);
    scan23<<<137, 256, 0, stream>>>(bsums, row_ptr);

    gemm_fill<<<1250 + 3907, 256, 0, stream>>>(img_feat, WtImg, img_b,
                                               txt_feat, WtTxt, txt_b, Xa,
                                               ei, ew, row_ptr, rank, epk);

    propagate<false><<<8750, 256, 0, stream>>>(Xa, row_ptr, epk, Xb);
    propagate<true ><<<8750, 256, 0, stream>>>(Xb, row_ptr, epk, out);
}

// Round 20
// 287.639 us; speedup vs baseline: 2.5867x; 1.0199x over previous
//
#include <hip/hip_runtime.h>

#define N_USERS 100000
#define N_ITEMS 40000
#define NN      140000          // N_NODES
#define N_EDGES 1000000
#define ALPHA   0.2f

typedef short bf16x8 __attribute__((ext_vector_type(8)));
typedef float f32x4  __attribute__((ext_vector_type(4)));

__device__ __forceinline__ unsigned short f2b(float x) {
    unsigned u = __builtin_bit_cast(unsigned, x);
    unsigned r = (u + 0x7FFFu + ((u >> 16) & 1u)) >> 16;
    return (unsigned short)r;
}
__device__ __forceinline__ unsigned cvtpk(float lo, float hi) {   // 2xf32 -> packed bf16 (RNE)
    unsigned r;
    asm("v_cvt_pk_bf16_f32 %0, %1, %2" : "=v"(r) : "v"(lo), "v"(hi));
    return r;
}
__device__ __forceinline__ float blo(unsigned u) { return __builtin_bit_cast(float, u << 16); }
__device__ __forceinline__ float bhi(unsigned u) { return __builtin_bit_cast(float, u & 0xFFFF0000u); }

// async global->LDS, 16B per lane; dest = wave-uniform base + lane*16 (HW rule)
__device__ __forceinline__ void gl_lds16(const void* g, void* l) {
    __builtin_amdgcn_global_load_lds(
        (const __attribute__((address_space(1))) void*)g,
        (__attribute__((address_space(3))) void*)l, 16, 0, 0);
}

// ---------------------------------------------------------------------------
// prep: block-range fused  [copy_pref | conv_w(img) | conv_w(txt) | hist+rank]
#define PREP_CP   6250
#define PREP_CI   (PREP_CP + 512)
#define PREP_CT   (PREP_CI + 96)
#define PREP_ALL  (PREP_CT + 3907)

// W[K][64] f32 -> Wt bf16, lane-ordered 1KB chunks
__device__ __forceinline__ int wt_pos(int k, int n) {
    return ((k >> 5) * 4 + (n >> 4)) * 512 + ((((k >> 3) & 3) * 16) + (n & 15)) * 8 + (k & 7);
}

__global__ __launch_bounds__(256)
void prep(const float* __restrict__ imgp, const float* __restrict__ txtp,
          unsigned short* __restrict__ X,
          const float* __restrict__ Wi, short* __restrict__ WtImg,
          const float* __restrict__ Wx, short* __restrict__ WtTxt,
          const int* __restrict__ ei, int* __restrict__ deg,
          int* __restrict__ rank)
{
    int b = blockIdx.x, t = threadIdx.x;
    if (b < PREP_CP) {
        int tid = b * 256 + t;                   // N_USERS*16 8-dim chunks
        if (tid >= N_USERS * 16) return;
        int i  = tid >> 4;
        int c8 = tid & 15;
        const float* src = (c8 < 8) ? &imgp[(size_t)i * 64 + c8 * 8]
                                    : &txtp[(size_t)i * 64 + (c8 - 8) * 8];
        float4 a = *reinterpret_cast<const float4*>(src);
        float4 c = *reinterpret_cast<const float4*>(src + 4);
        int4 o = make_int4((int)cvtpk(a.x, a.y), (int)cvtpk(a.z, a.w),
                           (int)cvtpk(c.x, c.y), (int)cvtpk(c.z, c.w));
        *reinterpret_cast<int4*>(&X[(size_t)i * 128 + c8 * 8]) = o;
    } else if (b < PREP_CI) {
        int tid = (b - PREP_CP) * 256 + t;       // 2048*64
        int k = tid >> 6, n = tid & 63;
        WtImg[wt_pos(k, n)] = (short)f2b(Wi[tid]);
    } else if (b < PREP_CT) {
        int tid = (b - PREP_CI) * 256 + t;       // 384*64
        if (tid >= 384 * 64) return;
        int k = tid >> 6, n = tid & 63;
        WtTxt[wt_pos(k, n)] = (short)f2b(Wx[tid]);
    } else {
        int e = (b - PREP_CT) * 256 + t;
        if (e < N_EDGES) {
            int d = ei[N_EDGES + e];
            int r = atomicAdd(&deg[d], 1);       // histogram AND this edge's rank
            rank[e] = r;                         // fire-and-forget store
        }
    }
}

// ---------------------------------------------------------------------------
// MFMA GEMM body (R15-proven BK=64 all-LDS counted-vmcnt pipeline), extended
// with split-K: block (rb, c) computes rows rb*64..+63 over k in [c*KCH, +KCH).
// SPLIT=true  -> write raw f32 partials to P[c][40000][64]
// SPLIT=false -> full epilogue (bias + L2-norm) into bf16 X at COLOFF.
template<int K, int KCH, int COLOFF, bool SPLIT>
__device__ __forceinline__
void gemm_body(int rb, int c, const float* __restrict__ A, const short* __restrict__ Wt,
               const float* __restrict__ bias, unsigned short* __restrict__ X,
               float* __restrict__ P, float* ldsA, short* ldsB)
{
    constexpr int NT = KCH / 64;      // img-split: 8, txt: 6
    const int t    = threadIdx.x;     // 0..255
    const int wid  = t >> 6;
    const int lane = t & 63;
    const int lo   = lane & 15;
    const int g    = lane >> 4;
    const int r0   = rb * 64;
    const int kb   = c * KCH;         // k base
    const int tb   = c * NT;          // Wt tile base

    f32x4 acc[4];
    #pragma unroll
    for (int ct = 0; ct < 4; ++ct) acc[ct] = (f32x4){0.f, 0.f, 0.f, 0.f};

    auto stage = [&](int buf, int kt) {
        int k0 = kb + kt * 64;
        #pragma unroll
        for (int i = 0; i < 4; ++i) {
            int cc    = i * 4 + wid;               // A chunk (4 rows x 16 units)
            int row_t = cc * 4 + g;
            int u_log = lo ^ (row_t & 15);
            const float* gp = A + (size_t)(r0 + row_t) * K + k0 + u_log * 4;
            gl_lds16(gp, ldsA + buf * 4096 + cc * 256);
        }
        #pragma unroll
        for (int i2 = 0; i2 < 2; ++i2) {
            int c2 = i2 * 4 + wid;                 // B chunk (lane-ordered 1KB)
            const short* gp = Wt + ((size_t)(tb + kt) * 8 + c2) * 512 + lane * 8;
            gl_lds16(gp, ldsB + buf * 4096 + c2 * 512);
        }
    };

    auto compute = [&](int buf) {
        int row_t = wid * 16 + lo;
        const float* baseA = ldsA + buf * 4096 + row_t * 64;
        const short* baseB = ldsB + buf * 4096;
        #pragma unroll
        for (int m = 0; m < 2; ++m) {
            int u0 = (m * 8 + 2 * g) ^ lo;         // swizzled A read
            int u1 = (m * 8 + 2 * g + 1) ^ lo;
            float4 xa = *reinterpret_cast<const float4*>(baseA + u0 * 4);
            float4 ya = *reinterpret_cast<const float4*>(baseA + u1 * 4);
            int4 ai = make_int4((int)cvtpk(xa.x, xa.y), (int)cvtpk(xa.z, xa.w),
                                (int)cvtpk(ya.x, ya.y), (int)cvtpk(ya.z, ya.w));
            bf16x8 a = __builtin_bit_cast(bf16x8, ai);
            #pragma unroll
            for (int ct = 0; ct < 4; ++ct) {
                int4 w = *reinterpret_cast<const int4*>(baseB + (m * 4 + ct) * 512 + lane * 8);
                bf16x8 bb = __builtin_bit_cast(bf16x8, w);
                acc[ct] = __builtin_amdgcn_mfma_f32_16x16x32_bf16(a, bb, acc[ct], 0, 0, 0);
            }
        }
    };

    stage(0, 0);                                    // 6 loads in flight
    for (int kt = 0; kt < NT; ++kt) {
        if (kt + 1 < NT) {
            stage((kt + 1) & 1, kt + 1);            // +6 loads (12 outstanding)
            asm volatile("s_waitcnt vmcnt(6)" ::: "memory");   // tile kt landed
        } else {
            asm volatile("s_waitcnt vmcnt(0)" ::: "memory");
        }
        __builtin_amdgcn_s_barrier();
        __builtin_amdgcn_sched_barrier(0);
        compute(kt & 1);
        __builtin_amdgcn_s_barrier();
    }

    int r0w = r0 + wid * 16;
    if (SPLIT) {
        // raw partial tile -> P[c][row][col], f32
        #pragma unroll
        for (int r = 0; r < 4; ++r) {
            int grow = r0w + g * 4 + r;
            float* dst = P + ((size_t)c * 40000 + grow) * 64 + lo;
            #pragma unroll
            for (int ct = 0; ct < 4; ++ct) dst[ct * 16] = acc[ct][r];
        }
    } else {
        float bia[4];
        #pragma unroll
        for (int ct = 0; ct < 4; ++ct) bia[ct] = bias[ct * 16 + lo];
        #pragma unroll
        for (int r = 0; r < 4; ++r) {
            float v[4];
            float ss = 0.f;
            #pragma unroll
            for (int ct = 0; ct < 4; ++ct) { v[ct] = acc[ct][r] + bia[ct]; ss += v[ct] * v[ct]; }
            ss += __shfl_xor(ss, 1);
            ss += __shfl_xor(ss, 2);
            ss += __shfl_xor(ss, 4);
            ss += __shfl_xor(ss, 8);
            float sc = 1.0f / fmaxf(sqrtf(ss), 1e-12f);
            int grow = r0w + g * 4 + r;
            unsigned short* dst = &X[(size_t)(N_USERS + grow) * 128 + COLOFF + lo];
            #pragma unroll
            for (int ct = 0; ct < 4; ++ct) dst[ct * 16] = f2b(v[ct] * sc);
        }
    }
}

// split mode: blocks 0..2499 img chunks (rb=b>>2, c=b&3), 2500..3124 txt,
// 3125.. fill (atomic-free)
__global__ __launch_bounds__(256)
void gemm_fill_split(const float* __restrict__ Ai, const short* __restrict__ WtImg,
                     const float* __restrict__ bi,
                     const float* __restrict__ Ax, const short* __restrict__ WtTxt,
                     const float* __restrict__ bx, unsigned short* __restrict__ X,
                     float* __restrict__ P,
                     const int* __restrict__ ei, const float* __restrict__ ew,
                     const int* __restrict__ row_ptr, const int* __restrict__ rank,
                     int2* __restrict__ epk)
{
    __shared__ float ldsA[8192];                   // 2 x 16KB
    __shared__ __align__(16) short ldsB[8192];     // 2 x 8KB
    int b = blockIdx.x;
    if (b < 2500) {
        gemm_body<2048, 512, 0, true>(b >> 2, b & 3, Ai, WtImg, bi, X, P, ldsA, ldsB);
    } else if (b < 3125) {
        gemm_body<384, 384, 64, false>(b - 2500, 0, Ax, WtTxt, bx, X, P, ldsA, ldsB);
    } else {
        int e = (b - 3125) * 256 + threadIdx.x;
        if (e >= N_EDGES) return;
        int s = ei[e];
        int d = ei[N_EDGES + e];
        int p = row_ptr[d] + rank[e];
        epk[p] = make_int2(s, __builtin_bit_cast(int, ew[e]));
    }
}

// flat fallback (R15 structure) if workspace can't hold P
__global__ __launch_bounds__(256)
void gemm_fill_flat(const float* __restrict__ Ai, const short* __restrict__ WtImg,
                    const float* __restrict__ bi,
                    const float* __restrict__ Ax, const short* __restrict__ WtTxt,
                    const float* __restrict__ bx, unsigned short* __restrict__ X,
                    const int* __restrict__ ei, const float* __restrict__ ew,
                    const int* __restrict__ row_ptr, const int* __restrict__ rank,
                    int2* __restrict__ epk)
{
    __shared__ float ldsA[8192];
    __shared__ __align__(16) short ldsB[8192];
    int b = blockIdx.x;
    if (b < 625)       gemm_body<2048, 2048, 0, false>(b, 0, Ai, WtImg, bi, X, nullptr, ldsA, ldsB);
    else if (b < 1250) gemm_body< 384,  384, 64, false>(b - 625, 0, Ax, WtTxt, bx, X, nullptr, ldsA, ldsB);
    else {
        int e = (b - 1250) * 256 + threadIdx.x;
        if (e >= N_EDGES) return;
        int s = ei[e];
        int d = ei[N_EDGES + e];
        int p = row_ptr[d] + rank[e];
        epk[p] = make_int2(s, __builtin_bit_cast(int, ew[e]));
    }
}

// sum 4 img partials + bias, L2-normalize, write bf16 X cols 0..63.
// one wave per row, 4 rows/block, grid 10000.
__global__ __launch_bounds__(256)
void reduce_norm(const float* __restrict__ P, const float* __restrict__ bias,
                 unsigned short* __restrict__ X)
{
    int lane = threadIdx.x & 63;
    int row  = blockIdx.x * 4 + (threadIdx.x >> 6);
    float v = P[(size_t)row * 64 + lane]
            + P[((size_t)40000  + row) * 64 + lane]
            + P[((size_t)80000  + row) * 64 + lane]
            + P[((size_t)120000 + row) * 64 + lane]
            + bias[lane];
    float ss = v * v;
    ss += __shfl_xor(ss, 1);
    ss += __shfl_xor(ss, 2);
    ss += __shfl_xor(ss, 4);
    ss += __shfl_xor(ss, 8);
    ss += __shfl_xor(ss, 16);
    ss += __shfl_xor(ss, 32);
    float sc = 1.0f / fmaxf(sqrtf(ss), 1e-12f);
    X[(size_t)(N_USERS + row) * 128 + lane] = f2b(v * sc);
}

// ---------------------------------------------------------------------------
// CSR scans
__global__ void scan1(const int* __restrict__ deg, int* __restrict__ row_ptr,
                      int* __restrict__ blockSums)
{
    __shared__ int ts[256];
    int t = threadIdx.x, b = blockIdx.x;
    int base = b * 1024 + t * 4;
    int v[4]; int s = 0;
    #pragma unroll
    for (int j = 0; j < 4; j++) {
        v[j] = (base + j < NN) ? deg[base + j] : 0;
        s += v[j];
    }
    ts[t] = s;
    __syncthreads();
    for (int off = 1; off < 256; off <<= 1) {
        int x = (t >= off) ? ts[t - off] : 0;
        __syncthreads();
        ts[t] += x;
        __syncthreads();
    }
    int excl = ts[t] - s;
    int run = excl;
    #pragma unroll
    for (int j = 0; j < 4; j++) {
        if (base + j < NN) row_ptr[base + j] = run;
        run += v[j];
    }
    if (t == 255) blockSums[b] = ts[255];
}

__global__ void scan23(const int* __restrict__ blockSums, int* __restrict__ row_ptr)
{
    __shared__ int ts[256];
    int t = threadIdx.x, b = blockIdx.x;
    ts[t] = (t < b) ? blockSums[t] : 0;     // b <= 136 < 256
    __syncthreads();
    for (int off = 128; off > 0; off >>= 1) {
        if (t < off) ts[t] += ts[t + off];
        __syncthreads();
    }
    int off0 = ts[0];
    int base = b * 1024 + t * 4;
    #pragma unroll
    for (int j = 0; j < 4; j++) {
        int idx = base + j;
        if (idx < NN) row_ptr[idx] += off0;
    }
    if (b == 0 && t == 0) row_ptr[NN] = N_EDGES;
}

// ---------------------------------------------------------------------------
// Propagation: one 16-lane group per node; lane owns 8 of 128 dims (uint4).
template<bool FINAL>
__global__ __launch_bounds__(256)
void propagate(const unsigned short* __restrict__ Xin, const int* __restrict__ row_ptr,
               const int2* __restrict__ epk, void* __restrict__ outv)
{
    int lane = threadIdx.x & 63;
    int gl   = lane & 15;
    int gb   = lane & 48;
    int node = blockIdx.x * 16 + (threadIdx.x >> 4);   // 8750*16 = NN exactly
    int e0 = row_ptr[node];
    int e1 = row_ptr[node + 1];
    float a0 = 0.f, a1 = 0.f, a2 = 0.f, a3 = 0.f;
    float a4 = 0.f, a5 = 0.f, a6 = 0.f, a7 = 0.f;

    for (int base = e0; base < e1; base += 16) {
        int cnt = e1 - base; if (cnt > 16) cnt = 16;
        int sv = 0, wvb = 0;
        if (base + gl < e1) {
            int2 ev = epk[base + gl];
            sv = ev.x; wvb = ev.y;
        }
        float wv = __builtin_bit_cast(float, wvb);
        int i = 0;
        for (; i + 1 < cnt; i += 2) {
            int   s0 = __shfl(sv, gb + i);
            int   s1 = __shfl(sv, gb + i + 1);
            float w0 = __shfl(wv, gb + i);
            float w1 = __shfl(wv, gb + i + 1);
            uint4 u0 = *reinterpret_cast<const uint4*>(&Xin[(size_t)s0 * 128 + gl * 8]);
            uint4 u1 = *reinterpret_cast<const uint4*>(&Xin[(size_t)s1 * 128 + gl * 8]);
            a0 = fmaf(w0, blo(u0.x), a0); a1 = fmaf(w0, bhi(u0.x), a1);
            a2 = fmaf(w0, blo(u0.y), a2); a3 = fmaf(w0, bhi(u0.y), a3);
            a4 = fmaf(w0, blo(u0.z), a4); a5 = fmaf(w0, bhi(u0.z), a5);
            a6 = fmaf(w0, blo(u0.w), a6); a7 = fmaf(w0, bhi(u0.w), a7);
            a0 = fmaf(w1, blo(u1.x), a0); a1 = fmaf(w1, bhi(u1.x), a1);
            a2 = fmaf(w1, blo(u1.y), a2); a3 = fmaf(w1, bhi(u1.y), a3);
            a4 = fmaf(w1, blo(u1.z), a4); a5 = fmaf(w1, bhi(u1.z), a5);
            a6 = fmaf(w1, blo(u1.w), a6); a7 = fmaf(w1, bhi(u1.w), a7);
        }
        if (i < cnt) {
            int   s0 = __shfl(sv, gb + i);
            float w0 = __shfl(wv, gb + i);
            uint4 u0 = *reinterpret_cast<const uint4*>(&Xin[(size_t)s0 * 128 + gl * 8]);
            a0 = fmaf(w0, blo(u0.x), a0); a1 = fmaf(w0, bhi(u0.x), a1);
            a2 = fmaf(w0, blo(u0.y), a2); a3 = fmaf(w0, bhi(u0.y), a3);
            a4 = fmaf(w0, blo(u0.z), a4); a5 = fmaf(w0, bhi(u0.z), a5);
            a6 = fmaf(w0, blo(u0.w), a6); a7 = fmaf(w0, bhi(u0.w), a7);
        }
    }

    uint4 us = *reinterpret_cast<const uint4*>(&Xin[(size_t)node * 128 + gl * 8]);
    a0 += ALPHA * blo(us.x); a1 += ALPHA * bhi(us.x);
    a2 += ALPHA * blo(us.y); a3 += ALPHA * bhi(us.y);
    a4 += ALPHA * blo(us.z); a5 += ALPHA * bhi(us.z);
    a6 += ALPHA * blo(us.w); a7 += ALPHA * bhi(us.w);

    if (!FINAL) {
        unsigned short* out = (unsigned short*)outv;
        uint4 p;
        p.x = cvtpk(a0, a1); p.y = cvtpk(a2, a3);
        p.z = cvtpk(a4, a5); p.w = cvtpk(a6, a7);
        *reinterpret_cast<uint4*>(&out[(size_t)node * 128 + gl * 8]) = p;
    } else {
        float* out = (float*)outv;
        int d = gl * 8;
        float* dst = (d < 64) ? &out[(size_t)node * 64 + d]
                              : &out[(size_t)NN * 64 + (size_t)node * 64 + (d - 64)];
        *reinterpret_cast<float4*>(dst)     = make_float4(a0, a1, a2, a3);
        *reinterpret_cast<float4*>(dst + 4) = make_float4(a4, a5, a6, a7);
    }
}

// ---------------------------------------------------------------------------
extern "C" void kernel_launch(void* const* d_in, const int* in_sizes, int n_in,
                              void* d_out, int out_size, void* d_ws, size_t ws_size,
                              hipStream_t stream)
{
    const int*   ei       = (const int*)d_in[0];
    const float* ew       = (const float*)d_in[1];
    const float* img_feat = (const float*)d_in[2];
    const float* txt_feat = (const float*)d_in[3];
    const float* img_w    = (const float*)d_in[4];
    const float* img_b    = (const float*)d_in[5];
    const float* txt_w    = (const float*)d_in[6];
    const float* txt_b    = (const float*)d_in[7];
    const float* img_pref = (const float*)d_in[8];
    const float* txt_pref = (const float*)d_in[9];
    float* out = (float*)d_out;

    const size_t XBYTES = (size_t)NN * 128 * 2;      // bf16
    const size_t PBYTES = (size_t)4 * 40000 * 64 * 4; // 40.96 MB f32 partials
    char* ws = (char*)d_ws;
    size_t off = 0;
    auto alloc = [&](size_t bytes) -> void* {
        void* p = ws + off;
        off = (off + bytes + 255) & ~(size_t)255;
        return p;
    };
    unsigned short* Xa = (unsigned short*)alloc(XBYTES);
    unsigned short* Xb = (unsigned short*)alloc(XBYTES);
    int*   deg     = (int*)alloc((size_t)NN * 4);
    int*   row_ptr = (int*)alloc((size_t)(NN + 1) * 4);
    int*   rank    = (int*)alloc((size_t)N_EDGES * 4);
    int2*  epk     = (int2*)alloc((size_t)N_EDGES * 8);
    int*   bsums   = (int*)alloc(256 * 4);
    short* WtImg   = (short*)alloc((size_t)2048 * 64 * 2);
    short* WtTxt   = (short*)alloc((size_t)384 * 64 * 2);
    bool haveP = (off + PBYTES) <= ws_size;
    float* P = haveP ? (float*)alloc(PBYTES) : nullptr;

    hipMemsetAsync(deg, 0, (size_t)NN * 4, stream);

    prep<<<PREP_ALL, 256, 0, stream>>>(img_pref, txt_pref, Xa,
                                       img_w, WtImg, txt_w, WtTxt, ei, deg, rank);

    scan1<<<137, 256, 0, stream>>>(deg, row_ptr, bsums);
    scan23<<<137, 256, 0, stream>>>(bsums, row_ptr);

    if (haveP) {
        gemm_fill_split<<<3125 + 3907, 256, 0, stream>>>(
            img_feat, WtImg, img_b, txt_feat, WtTxt, txt_b, Xa, P,
            ei, ew, row_ptr, rank, epk);
        reduce_norm<<<10000, 256, 0, stream>>>(P, img_b, Xa);
    } else {
        gemm_fill_flat<<<1250 + 3907, 256, 0, stream>>>(
            img_feat, WtImg, img_b, txt_feat, WtTxt, txt_b, Xa,
            ei, ew, row_ptr, rank, epk);
    }

    propagate<false><<<8750, 256, 0, stream>>>(Xa, row_ptr, epk, Xb);
    propagate<true ><<<8750, 256, 0, stream>>>(Xb, row_ptr, epk, out);
}